// Round 7
// baseline (655.888 us; speedup 1.0000x reference)
//
#include <hip/hip_runtime.h>

#define NWIN 1024
#define LTOK 256
#define EMB  192
#define NPAT 64
#define NHEAD 6
#define HDIM 32
#define SCALE 0.08838834764831845f
#define LN_EPS 1e-5f

typedef float f32x4 __attribute__((ext_vector_type(4)));
typedef short s16x8 __attribute__((ext_vector_type(8)));

// ---- attention kernel LDS layout (bytes) ----
#define OFF_VT0 0        // [128 sc][64 k] bf16, row 128B, swz ((sc&7)<<4)
#define OFF_VT1 16384    // second V buffer (double-buffered across heads)
#define OFF_PB  32768    // [64 q][64 k] bf16 (unnormalized e), row 128B, swz ((q&7)<<4)
#define OFF_OB  40960    // [64 q] x 272B rows (128 sc bf16) ; also phase1 partials
#define OFF_ST  58368    // stats: 6 x 64 f32
#define OFF_HB  59904    // [64 q][2 half] float2 (m,s) = 1024B
#define SMEM_BYTES 60928
#define OBSTRIDE 272

__device__ __forceinline__ unsigned short f2bf(float f) {
    unsigned u = __float_as_uint(f);
    u += 0x7fffu + ((u >> 16) & 1u);
    return (unsigned short)(u >> 16);
}

__device__ __forceinline__ int tok_of(int p, int s) {
    // t = wh*32 + sh*16 + ww*2 + sw ; p = wh*8+ww, s = sh*2+sw
    return ((p >> 3) << 5) + ((s >> 1) << 4) + ((p & 7) << 1) + (s & 1);
}

__device__ __forceinline__ f32x4 mfma16(s16x8 a, s16x8 b, f32x4 c) {
    return __builtin_amdgcn_mfma_f32_16x16x32_bf16(a, b, c, 0, 0, 0);
}

__device__ __forceinline__ s16x8 ln_pack8r(const float* v, float mu, float rs,
                                           const float* __restrict__ wl,
                                           const float* __restrict__ bl,
                                           float scale) {
    f32x4 w0 = *(const f32x4*)wl;
    f32x4 w1 = *(const f32x4*)(wl + 4);
    f32x4 c0 = *(const f32x4*)bl;
    f32x4 c1 = *(const f32x4*)(bl + 4);
    s16x8 r;
    r[0] = (short)f2bf(((v[0]-mu)*rs*w0[0] + c0[0])*scale);
    r[1] = (short)f2bf(((v[1]-mu)*rs*w0[1] + c0[1])*scale);
    r[2] = (short)f2bf(((v[2]-mu)*rs*w0[2] + c0[2])*scale);
    r[3] = (short)f2bf(((v[3]-mu)*rs*w0[3] + c0[3])*scale);
    r[4] = (short)f2bf(((v[4]-mu)*rs*w1[0] + c1[0])*scale);
    r[5] = (short)f2bf(((v[5]-mu)*rs*w1[1] + c1[1])*scale);
    r[6] = (short)f2bf(((v[6]-mu)*rs*w1[2] + c1[2])*scale);
    r[7] = (short)f2bf(((v[7]-mu)*rs*w1[3] + c1[3])*scale);
    return r;
}

__device__ __forceinline__ void ln_f8r(const float* v, float mu, float rs,
                                       const float* __restrict__ wl,
                                       const float* __restrict__ bl,
                                       float* o) {
    f32x4 w0 = *(const f32x4*)wl;
    f32x4 w1 = *(const f32x4*)(wl + 4);
    f32x4 c0 = *(const f32x4*)bl;
    f32x4 c1 = *(const f32x4*)(bl + 4);
    o[0] = (v[0]-mu)*rs*w0[0] + c0[0];
    o[1] = (v[1]-mu)*rs*w0[1] + c0[1];
    o[2] = (v[2]-mu)*rs*w0[2] + c0[2];
    o[3] = (v[3]-mu)*rs*w0[3] + c0[3];
    o[4] = (v[4]-mu)*rs*w1[0] + c1[0];
    o[5] = (v[5]-mu)*rs*w1[1] + c1[1];
    o[6] = (v[6]-mu)*rs*w1[2] + c1[2];
    o[7] = (v[7]-mu)*rs*w1[3] + c1[3];
}

__device__ __forceinline__ void vload(float vld[2][8], const float* __restrict__ v_g,
                                      size_t wbase, int tid, int hh) {
    int p = tid & 63;
    #pragma unroll
    for (int i = 0; i < 2; ++i) {
        int scb = (tid >> 6) * 2 + i;
        int s = scb >> 2, cbx = scb & 3;
        const float* vp = v_g + wbase + tok_of(p, s)*EMB + hh*HDIM + cbx*8;
        *(f32x4*)&vld[i][0] = *(const f32x4*)vp;
        *(f32x4*)&vld[i][4] = *(const f32x4*)(vp + 4);
    }
}

__device__ __forceinline__ void vstage(char* vt, const float vld[2][8], int tid, int hh,
                                       const float* stats,
                                       const float* __restrict__ lnvw,
                                       const float* __restrict__ lnvb) {
    int p = tid & 63;
    float muv = stats[256 + p], rsv = stats[320 + p];
    #pragma unroll
    for (int i = 0; i < 2; ++i) {
        int scb = (tid >> 6) * 2 + i;
        int s = scb >> 2, cbx = scb & 3;
        int chb = hh*HDIM + cbx*8;
        float vn[8];
        ln_f8r(vld[i], muv, rsv, lnvw + s*EMB + chb, lnvb + s*EMB + chb, vn);
        #pragma unroll
        for (int j = 0; j < 8; ++j) {
            int sc = scb*8 + j;
            *(unsigned short*)(vt + sc*128 + ((p*2) ^ ((sc & 7) << 4))) = f2bf(vn[j]);
        }
    }
}

// Pre-projection bf16 lives INSIDE d_out: window w bytes [w*196608+98304, +98304)
// layout [h:6][qp:64][sc:128] bf16. proj reads it into regs before overwriting.

__global__ __launch_bounds__(512, 4) void dwa_attn_kernel(
    const float* __restrict__ q_g, const float* __restrict__ k_g,
    const float* __restrict__ v_g, const float* __restrict__ mask_g,
    const float* __restrict__ lnqw, const float* __restrict__ lnqb,
    const float* __restrict__ lnkw, const float* __restrict__ lnkb,
    const float* __restrict__ lnvw, const float* __restrict__ lnvb,
    const float* __restrict__ btab, float* __restrict__ out_g)
{
    __shared__ __align__(16) char smem[SMEM_BYTES];

    const int tid  = threadIdx.x;
    const int lane = tid & 63;
    const int wv   = tid >> 6;
    const int win  = blockIdx.x;
    const size_t wbase = (size_t)win * LTOK * EMB;
    char* preb = (char*)out_g + (size_t)win * 196608 + 98304;

    float* stats = (float*)(smem + OFF_ST);
    const int l15 = lane & 15, l4 = lane >> 4;
    const int qt = wv >> 1, half = wv & 1;
    const int qA  = qt*16 + l15;            // query patch (stepA col / stepB col)
    const int kA0 = (half*2 + 0)*16 + l15;  // K patches (stepA rows)
    const int kA1 = kA0 + 16;

    // ---- per-lane mask regs + bias table indices (head-invariant) ----
    const float* mask_w = mask_g + (size_t)(win & 63) * NPAT * NPAT;
    f32x4 mk0 = *(const f32x4*)(mask_w + qA*64 + (half*2+0)*16 + l4*4);
    f32x4 mk1 = *(const f32x4*)(mask_w + qA*64 + (half*2+1)*16 + l4*4);
    int bidx[8];
    {
        int qh = qA >> 3, qw = qA & 7;
        #pragma unroll
        for (int kt = 0; kt < 2; ++kt)
            #pragma unroll
            for (int r = 0; r < 4; ++r) {
                int kc = (half*2 + kt)*16 + l4*4 + r;
                bidx[kt*4+r] = ((qh - (kc>>3) + 7)*15 + (qw - (kc&7) + 7)) * NHEAD;
            }
    }

    // ---------------- Phase 1: LN stats for q,k,v (single pass) ----------------
    {
        float* part = (float*)(smem + OFF_OB);   // [256 t][2 half][6] = 12KB
        const int t = tid >> 1, hlf = tid & 1;
        const f32x4* qp = (const f32x4*)(q_g + wbase + t*EMB + hlf*96);
        const f32x4* kp = (const f32x4*)(k_g + wbase + t*EMB + hlf*96);
        const f32x4* vp = (const f32x4*)(v_g + wbase + t*EMB + hlf*96);
        float s1q=0.f,s2q=0.f,s1k=0.f,s2k=0.f,s1v=0.f,s2v=0.f;
        #pragma unroll 4
        for (int i = 0; i < 24; ++i) {
            f32x4 a = qp[i];
            s1q += a[0]+a[1]+a[2]+a[3];
            s2q += a[0]*a[0]+a[1]*a[1]+a[2]*a[2]+a[3]*a[3];
            f32x4 b = kp[i];
            s1k += b[0]+b[1]+b[2]+b[3];
            s2k += b[0]*b[0]+b[1]*b[1]+b[2]*b[2]+b[3]*b[3];
            f32x4 c = vp[i];
            s1v += c[0]+c[1]+c[2]+c[3];
            s2v += c[0]*c[0]+c[1]*c[1]+c[2]*c[2]+c[3]*c[3];
        }
        float* pp = part + (t*2 + hlf)*6;
        pp[0]=s1q; pp[1]=s2q; pp[2]=s1k; pp[3]=s2k; pp[4]=s1v; pp[5]=s2v;
        __syncthreads();
        if (tid < NPAT) {
            float S[6] = {0.f,0.f,0.f,0.f,0.f,0.f};
            #pragma unroll
            for (int s = 0; s < 4; ++s) {
                int tt = tok_of(tid, s);
                const float* pr_ = part + tt*12;
                #pragma unroll
                for (int x = 0; x < 6; ++x) S[x] += pr_[x] + pr_[6 + x];
            }
            #pragma unroll
            for (int x = 0; x < 3; ++x) {
                float mu  = S[2*x] * (1.f/768.f);
                float var = S[2*x+1] * (1.f/768.f) - mu*mu;
                stats[x*128 + tid]      = mu;
                stats[x*128 + 64 + tid] = rsqrtf(var + LN_EPS);
            }
        }
        __syncthreads();
    }

    // ---------------- Prologue: stage V for head 0 into VT0 ----------------
    {
        float vld[2][8];
        vload(vld, v_g, wbase, tid, 0);
        vstage(smem + OFF_VT0, vld, tid, 0, stats, lnvw, lnvb);
        // visible to PV(0) via stepA's barrier
    }

    const float muqv = stats[qA],       rsqv = stats[64 + qA];
    const float muk0 = stats[128 + kA0], rsk0 = stats[192 + kA0];
    const float muk1 = stats[128 + kA1], rsk1 = stats[192 + kA1];

    // ---------------- Head loop: 2 barriers per head ----------------
    for (int h = 0; h < NHEAD; ++h) {
        // ---- stepA: bias gather + QK^T (swapped, direct-global) + softmax ----
        float bload[8];
        #pragma unroll
        for (int i = 0; i < 8; ++i) bload[i] = btab[bidx[i] + h];

        f32x4 acc0 = {0.f,0.f,0.f,0.f};
        f32x4 acc1 = {0.f,0.f,0.f,0.f};
        {
            const int ch = h*HDIM + l4*8;
            #pragma unroll
            for (int ks = 0; ks < 4; ++ks) {
                const float* qp_ = q_g + wbase + tok_of(qA,  ks)*EMB + ch;
                const float* kp0 = k_g + wbase + tok_of(kA0, ks)*EMB + ch;
                const float* kp1 = k_g + wbase + tok_of(kA1, ks)*EMB + ch;
                float qv[8], kv0[8], kv1[8];
                *(f32x4*)&qv[0]  = *(const f32x4*)qp_;
                *(f32x4*)&qv[4]  = *(const f32x4*)(qp_ + 4);
                *(f32x4*)&kv0[0] = *(const f32x4*)kp0;
                *(f32x4*)&kv0[4] = *(const f32x4*)(kp0 + 4);
                *(f32x4*)&kv1[0] = *(const f32x4*)kp1;
                *(f32x4*)&kv1[4] = *(const f32x4*)(kp1 + 4);
                const float* lwq = lnqw + ks*EMB + ch;
                const float* lbq = lnqb + ks*EMB + ch;
                const float* lwk = lnkw + ks*EMB + ch;
                const float* lbk = lnkb + ks*EMB + ch;
                s16x8 bf = ln_pack8r(qv,  muqv, rsqv, lwq, lbq, SCALE);
                s16x8 a0 = ln_pack8r(kv0, muk0, rsk0, lwk, lbk, 1.0f);
                s16x8 a1 = ln_pack8r(kv1, muk1, rsk1, lwk, lbk, 1.0f);
                acc0 = mfma16(a0, bf, acc0);
                acc1 = mfma16(a1, bf, acc1);
            }
        }
        {
            float P[8];
            #pragma unroll
            for (int r = 0; r < 4; ++r) {
                P[r]   = acc0[r] + mk0[r] + bload[r];
                P[4+r] = acc1[r] + mk1[r] + bload[4+r];
            }
            float m = fmaxf(fmaxf(fmaxf(P[0],P[1]), fmaxf(P[2],P[3])),
                            fmaxf(fmaxf(P[4],P[5]), fmaxf(P[6],P[7])));
            m = fmaxf(m, __shfl_xor(m, 16));
            m = fmaxf(m, __shfl_xor(m, 32));
            float s = 0.f;
            #pragma unroll
            for (int i = 0; i < 8; ++i) { P[i] = __expf(P[i] - m); s += P[i]; }
            s += __shfl_xor(s, 16);
            s += __shfl_xor(s, 32);
            if (l4 == 0) {
                float2 v; v.x = m; v.y = s;
                *(float2*)(smem + OFF_HB + qA*16 + half*8) = v;
            }
            #pragma unroll
            for (int kt = 0; kt < 2; ++kt) {
                uint2 pk;
                pk.x = (unsigned)f2bf(P[kt*4+0]) | ((unsigned)f2bf(P[kt*4+1]) << 16);
                pk.y = (unsigned)f2bf(P[kt*4+2]) | ((unsigned)f2bf(P[kt*4+3]) << 16);
                *(uint2*)(smem + OFF_PB + qA*128 +
                    (((half*2 + kt)*32 + l4*8) ^ ((qA & 7) << 4))) = pk;
            }
        }
        __syncthreads();   // barrier 1: PB + HB ready; VT(h) writes visible

        // ---- stepB: PV (swapped) + rescale-combine + V restage ----
        float vld[2][8];
        if (h < NHEAD-1) vload(vld, v_g, wbase, tid, h+1);
        {
            f32x4 hb = *(const f32x4*)(smem + OFF_HB + qA*16); // m0,s0,m1,s1
            float M  = fmaxf(hb[0], hb[2]);
            float w0 = __expf(hb[0] - M), w1 = __expf(hb[2] - M);
            float Sv = 1.f / (hb[1]*w0 + hb[3]*w1);
            float f0 = w0*Sv, f1 = w1*Sv;
            s16x8 pb0 = *(const s16x8*)(smem + OFF_PB + qA*128 +
                          ((l4*16) ^ ((qA & 7) << 4)));
            s16x8 pb1 = *(const s16x8*)(smem + OFF_PB + qA*128 +
                          ((64 + l4*16) ^ ((qA & 7) << 4)));
            const char* vt = smem + ((h & 1) ? OFF_VT1 : OFF_VT0);
            __builtin_amdgcn_s_setprio(1);
            #pragma unroll
            for (int i = 0; i < 4; ++i) {
                int sct = half*4 + i;
                int scr = sct*16 + l15;
                s16x8 a0 = *(const s16x8*)(vt + scr*128 +
                              ((l4*16) ^ ((scr & 7) << 4)));
                s16x8 a1 = *(const s16x8*)(vt + scr*128 +
                              ((64 + l4*16) ^ ((scr & 7) << 4)));
                f32x4 z = {0.f,0.f,0.f,0.f};
                f32x4 c0 = mfma16(a0, pb0, z);
                f32x4 c1 = mfma16(a1, pb1, z);
                float o0 = f0*c0[0] + f1*c1[0];
                float o1 = f0*c0[1] + f1*c1[1];
                float o2 = f0*c0[2] + f1*c1[2];
                float o3 = f0*c0[3] + f1*c1[3];
                uint2 pk;
                pk.x = (unsigned)f2bf(o0) | ((unsigned)f2bf(o1) << 16);
                pk.y = (unsigned)f2bf(o2) | ((unsigned)f2bf(o3) << 16);
                *(uint2*)(smem + OFF_OB + qA*OBSTRIDE + sct*32 + l4*8) = pk;
            }
            __builtin_amdgcn_s_setprio(0);
        }
        if (h < NHEAD-1)
            vstage(smem + ((h & 1) ? OFF_VT0 : OFF_VT1), vld, tid, h+1,
                   stats, lnvw, lnvb);
        __syncthreads();   // barrier 2: OB ready; PB/HB reads done

        // ---- stepC: store this head's [qp][sc] slab as full 256B rows ----
        #pragma unroll
        for (int i = 0; i < 2; ++i) {
            int c = i*512 + tid;             // 1024 chunks of 16B
            int qp = c >> 4, ch2 = c & 15;
            s16x8 v = *(const s16x8*)(smem + OFF_OB + qp*OBSTRIDE + ch2*16);
            *(s16x8*)(preb + h*16384 + qp*256 + ch2*16) = v;
        }
        // OB next rewritten after h+1's barrier 1 -> safe without extra barrier
    }
}

// ---- projection: 1 block per window, W staged bf16 in LDS once ----
__global__ __launch_bounds__(256, 2) void dwa_proj_kernel(
    const float* __restrict__ pw, float* __restrict__ out_g)
{
    __shared__ __align__(16) char smem[73728];   // [192 orow][192 ch] bf16, swz

    const int tid  = threadIdx.x;
    const int lane = tid & 63;
    const int wv   = tid >> 6;
    const int w    = blockIdx.x;
    const char* preb = (const char*)out_g + (size_t)w * 196608 + 98304;
    const int cb = lane >> 4;

    // preload all A fragments from [h][qp][sc] pre layout (before staging barrier)
    s16x8 af[4][6];
    #pragma unroll
    for (int si = 0; si < 4; ++si) {
        int t = (wv*4 + si)*16 + (lane & 15);       // token row
        int qp = ((t >> 5) << 3) | ((t >> 1) & 7);
        int s  = (((t >> 4) & 1) << 1) | (t & 1);
        #pragma unroll
        for (int ks = 0; ks < 6; ++ks)
            af[si][ks] = *(const s16x8*)(preb + ks*16384 + qp*256 + s*64 + cb*16);
    }

    // stage W (192x192 f32 -> bf16), 4608 chunks of 8
    #pragma unroll 2
    for (int i = 0; i < 18; ++i) {
        int c = i*256 + tid;
        int orow = c / 24, cb8 = c % 24;
        const float* wp = pw + (size_t)orow*EMB + cb8*8;
        f32x4 a = *(const f32x4*)wp;
        f32x4 b = *(const f32x4*)(wp + 4);
        s16x8 w8;
        w8[0] = (short)f2bf(a[0]); w8[1] = (short)f2bf(a[1]);
        w8[2] = (short)f2bf(a[2]); w8[3] = (short)f2bf(a[3]);
        w8[4] = (short)f2bf(b[0]); w8[5] = (short)f2bf(b[1]);
        w8[6] = (short)f2bf(b[2]); w8[7] = (short)f2bf(b[3]);
        *(s16x8*)(smem + orow*384 + ((cb8*16) ^ ((orow & 7) << 4))) = w8;
    }
    __syncthreads();

    #pragma unroll
    for (int si = 0; si < 4; ++si) {
        int strip = wv*4 + si;
        #pragma unroll
        for (int nt = 0; nt < 12; ++nt) {
            int orow = nt*16 + (lane & 15);
            f32x4 acc = {0.f,0.f,0.f,0.f};
            #pragma unroll
            for (int ks = 0; ks < 6; ++ks) {
                s16x8 bf = *(const s16x8*)(smem + orow*384 +
                              ((ks*64 + cb*16) ^ ((orow & 7) << 4)));
                acc = mfma16(af[si][ks], bf, acc);
            }
            #pragma unroll
            for (int r = 0; r < 4; ++r) {
                int trow = strip*16 + (lane >> 4)*4 + r;
                out_g[(size_t)w*49152 + trow*EMB + nt*16 + (lane & 15)] = acc[r];
            }
        }
    }
}

extern "C" void kernel_launch(void* const* d_in, const int* in_sizes, int n_in,
                              void* d_out, int out_size, void* d_ws, size_t ws_size,
                              hipStream_t stream) {
    (void)in_sizes; (void)n_in; (void)out_size; (void)d_ws; (void)ws_size;
    dwa_attn_kernel<<<dim3(NWIN), dim3(512), 0, stream>>>(
        (const float*)d_in[0],  (const float*)d_in[1],  (const float*)d_in[2],
        (const float*)d_in[3],  (const float*)d_in[4],  (const float*)d_in[5],
        (const float*)d_in[6],  (const float*)d_in[7],  (const float*)d_in[8],
        (const float*)d_in[9],  (const float*)d_in[10],
        (float*)d_out);
    dwa_proj_kernel<<<dim3(NWIN), dim3(256), 0, stream>>>(
        (const float*)d_in[11], (float*)d_out);
}

// Round 8
// 522.602 us; speedup vs baseline: 1.2550x; 1.2550x over previous
//
#include <hip/hip_runtime.h>

#define NWIN 1024
#define LTOK 256
#define EMB  192
#define NPAT 64
#define NHEAD 6
#define HDIM 32
#define SCALE 0.08838834764831845f
#define LN_EPS 1e-5f

typedef float f32x4 __attribute__((ext_vector_type(4)));
typedef short s16x8 __attribute__((ext_vector_type(8)));

#define KN_BYTES 100663296ull   // 1024 * 6*64*128 * 2B (one bf16 tensor)

__device__ __forceinline__ unsigned short f2bf(float f) {
    unsigned u = __float_as_uint(f);
    u += 0x7fffu + ((u >> 16) & 1u);
    return (unsigned short)(u >> 16);
}

__device__ __forceinline__ int tok_of(int p, int s) {
    // t = wh*32 + sh*16 + ww*2 + sw ; p = wh*8+ww, s = sh*2+sw
    return ((p >> 3) << 5) + ((s >> 1) << 4) + ((p & 7) << 1) + (s & 1);
}

__device__ __forceinline__ f32x4 mfma16(s16x8 a, s16x8 b, f32x4 c) {
    return __builtin_amdgcn_mfma_f32_16x16x32_bf16(a, b, c, 0, 0, 0);
}

__device__ __forceinline__ s16x8 ln_pack8r(const float* v, float mu, float rs,
                                           const float* __restrict__ wl,
                                           const float* __restrict__ bl,
                                           float scale) {
    f32x4 w0 = *(const f32x4*)wl;
    f32x4 w1 = *(const f32x4*)(wl + 4);
    f32x4 c0 = *(const f32x4*)bl;
    f32x4 c1 = *(const f32x4*)(bl + 4);
    s16x8 r;
    r[0] = (short)f2bf(((v[0]-mu)*rs*w0[0] + c0[0])*scale);
    r[1] = (short)f2bf(((v[1]-mu)*rs*w0[1] + c0[1])*scale);
    r[2] = (short)f2bf(((v[2]-mu)*rs*w0[2] + c0[2])*scale);
    r[3] = (short)f2bf(((v[3]-mu)*rs*w0[3] + c0[3])*scale);
    r[4] = (short)f2bf(((v[4]-mu)*rs*w1[0] + c1[0])*scale);
    r[5] = (short)f2bf(((v[5]-mu)*rs*w1[1] + c1[1])*scale);
    r[6] = (short)f2bf(((v[6]-mu)*rs*w1[2] + c1[2])*scale);
    r[7] = (short)f2bf(((v[7]-mu)*rs*w1[3] + c1[3])*scale);
    return r;
}

__device__ __forceinline__ void ln_f8r(const float* v, float mu, float rs,
                                       const float* __restrict__ wl,
                                       const float* __restrict__ bl,
                                       float* o) {
    f32x4 w0 = *(const f32x4*)wl;
    f32x4 w1 = *(const f32x4*)(wl + 4);
    f32x4 c0 = *(const f32x4*)bl;
    f32x4 c1 = *(const f32x4*)(bl + 4);
    o[0] = (v[0]-mu)*rs*w0[0] + c0[0];
    o[1] = (v[1]-mu)*rs*w0[1] + c0[1];
    o[2] = (v[2]-mu)*rs*w0[2] + c0[2];
    o[3] = (v[3]-mu)*rs*w0[3] + c0[3];
    o[4] = (v[4]-mu)*rs*w1[0] + c1[0];
    o[5] = (v[5]-mu)*rs*w1[1] + c1[1];
    o[6] = (v[6]-mu)*rs*w1[2] + c1[2];
    o[7] = (v[7]-mu)*rs*w1[3] + c1[3];
}

__device__ __forceinline__ void vload(float vld[2][8], const float* __restrict__ v_g,
                                      size_t wbase, int tid, int hh) {
    int p = tid & 63;
    #pragma unroll
    for (int i = 0; i < 2; ++i) {
        int scb = (tid >> 6) * 2 + i;
        int s = scb >> 2, cbx = scb & 3;
        const float* vp = v_g + wbase + tok_of(p, s)*EMB + hh*HDIM + cbx*8;
        *(f32x4*)&vld[i][0] = *(const f32x4*)vp;
        *(f32x4*)&vld[i][4] = *(const f32x4*)(vp + 4);
    }
}

// writes normalized V as [sc:128][p:64] bf16 rows (128B) with ((sc&7)<<4) swizzle
__device__ __forceinline__ void vstage(char* vt, const float vld[2][8], int tid, int hh,
                                       const float* stats,
                                       const float* __restrict__ lnvw,
                                       const float* __restrict__ lnvb) {
    int p = tid & 63;
    float muv = stats[256 + p], rsv = stats[320 + p];
    #pragma unroll
    for (int i = 0; i < 2; ++i) {
        int scb = (tid >> 6) * 2 + i;
        int s = scb >> 2, cbx = scb & 3;
        int chb = hh*HDIM + cbx*8;
        float vn[8];
        ln_f8r(vld[i], muv, rsv, lnvw + s*EMB + chb, lnvb + s*EMB + chb, vn);
        #pragma unroll
        for (int j = 0; j < 8; ++j) {
            int sc = scb*8 + j;
            *(unsigned short*)(vt + sc*128 + ((p*2) ^ ((sc & 7) << 4))) = f2bf(vn[j]);
        }
    }
}

// =====================================================================
// Pass 1: LN-normalize q,k,v to bf16.
//   q_n -> d_out first half per window: [h][p][sc] bf16 (98304B/window)
//   k_n -> ws[0..KN):                    [h][p][sc] bf16
//   v_n -> ws[KN..2KN):                  [h][sc][p] bf16 (transposed)
// =====================================================================
__global__ __launch_bounds__(512, 2) void dwa_prep_kernel(
    const float* __restrict__ q_g, const float* __restrict__ k_g,
    const float* __restrict__ v_g,
    const float* __restrict__ lnqw, const float* __restrict__ lnqb,
    const float* __restrict__ lnkw, const float* __restrict__ lnkb,
    const float* __restrict__ lnvw, const float* __restrict__ lnvb,
    char* __restrict__ qn_g, char* __restrict__ kn_g, char* __restrict__ vn_g)
{
    __shared__ __align__(16) char smem[17920];  // [0,16384)=part/VT, [16384,+1536)=stats

    const int tid = threadIdx.x;
    const int win = blockIdx.x;
    const size_t wbase = (size_t)win * LTOK * EMB;
    float* stats = (float*)(smem + 16384);

    // ---- stats (single pass over q,k,v) ----
    {
        float* part = (float*)smem;   // [256 t][2 half][6]
        const int t = tid >> 1, hlf = tid & 1;
        const f32x4* qp = (const f32x4*)(q_g + wbase + t*EMB + hlf*96);
        const f32x4* kp = (const f32x4*)(k_g + wbase + t*EMB + hlf*96);
        const f32x4* vp = (const f32x4*)(v_g + wbase + t*EMB + hlf*96);
        float s1q=0.f,s2q=0.f,s1k=0.f,s2k=0.f,s1v=0.f,s2v=0.f;
        #pragma unroll 4
        for (int i = 0; i < 24; ++i) {
            f32x4 a = qp[i];
            s1q += a[0]+a[1]+a[2]+a[3];
            s2q += a[0]*a[0]+a[1]*a[1]+a[2]*a[2]+a[3]*a[3];
            f32x4 b = kp[i];
            s1k += b[0]+b[1]+b[2]+b[3];
            s2k += b[0]*b[0]+b[1]*b[1]+b[2]*b[2]+b[3]*b[3];
            f32x4 c = vp[i];
            s1v += c[0]+c[1]+c[2]+c[3];
            s2v += c[0]*c[0]+c[1]*c[1]+c[2]*c[2]+c[3]*c[3];
        }
        float* pp = part + (t*2 + hlf)*6;
        pp[0]=s1q; pp[1]=s2q; pp[2]=s1k; pp[3]=s2k; pp[4]=s1v; pp[5]=s2v;
        __syncthreads();
        if (tid < NPAT) {
            float S[6] = {0.f,0.f,0.f,0.f,0.f,0.f};
            #pragma unroll
            for (int s = 0; s < 4; ++s) {
                int tt = tok_of(tid, s);
                const float* pr_ = part + tt*12;
                #pragma unroll
                for (int x = 0; x < 6; ++x) S[x] += pr_[x] + pr_[6 + x];
            }
            #pragma unroll
            for (int x = 0; x < 3; ++x) {
                float mu  = S[2*x] * (1.f/768.f);
                float var = S[2*x+1] * (1.f/768.f) - mu*mu;
                stats[x*128 + tid]      = mu;
                stats[x*128 + 64 + tid] = rsqrtf(var + LN_EPS);
            }
        }
        __syncthreads();
    }

    char* qn = qn_g + (size_t)win * 196608;
    char* kn = kn_g + (size_t)win * 98304;
    char* vn = vn_g + (size_t)win * 98304;
    const float* muq = stats;       const float* rsq = stats + 64;
    const float* muk = stats + 128; const float* rsk = stats + 192;

    for (int h = 0; h < NHEAD; ++h) {
        // ---- q_n / k_n: [h][p][sc], coalesced 256B rows ----
        #pragma unroll
        for (int i = 0; i < 2; ++i) {
            int c = i*512 + tid;
            int p = c >> 4, scb = c & 15, s = scb >> 2, cbx = scb & 3;
            int t = tok_of(p, s), ch = h*HDIM + cbx*8;
            float xv[8];
            const float* src = q_g + wbase + t*EMB + ch;
            *(f32x4*)&xv[0] = *(const f32x4*)src;
            *(f32x4*)&xv[4] = *(const f32x4*)(src + 4);
            s16x8 r = ln_pack8r(xv, muq[p], rsq[p],
                                lnqw + s*EMB + ch, lnqb + s*EMB + ch, SCALE);
            *(s16x8*)(qn + (size_t)(h*64 + p)*256 + scb*16) = r;
            const float* ksrc = k_g + wbase + t*EMB + ch;
            *(f32x4*)&xv[0] = *(const f32x4*)ksrc;
            *(f32x4*)&xv[4] = *(const f32x4*)(ksrc + 4);
            r = ln_pack8r(xv, muk[p], rsk[p],
                          lnkw + s*EMB + ch, lnkb + s*EMB + ch, 1.0f);
            *(s16x8*)(kn + (size_t)(h*64 + p)*256 + scb*16) = r;
        }
        // ---- v_n: LDS transpose then coalesced [h][sc][p] rows ----
        float vld[2][8];
        vload(vld, v_g, wbase, tid, h);
        __syncthreads();                 // prior transpose reads / part done
        vstage(smem, vld, tid, h, stats, lnvw, lnvb);
        __syncthreads();                 // VT ready
        #pragma unroll
        for (int i = 0; i < 2; ++i) {
            int c = i*512 + tid;
            int sc = c >> 3, pb = c & 7;
            s16x8 vv = *(const s16x8*)(smem + sc*128 + ((pb*16) ^ ((sc & 7) << 4)));
            *(s16x8*)(vn + (size_t)(h*128 + sc)*128 + pb*16) = vv;
        }
    }
}

// =====================================================================
// Pass 2: attention from bf16 q_n/k_n/v_n (all operands direct global).
// LDS: PB [64q][64k] bf16 swz (8KB) | OB [64q]x272B (17KB) | HB 1KB
// =====================================================================
#define A2_PB 0
#define A2_OB 8192
#define A2_HB 25600
#define A2_SMEM 26624
#define A2_OBS 272

__global__ __launch_bounds__(512, 2) void dwa_attn2_kernel(
    const char* __restrict__ qn_g, const char* __restrict__ kn_g,
    const char* __restrict__ vn_g, const float* __restrict__ mask_g,
    const float* __restrict__ btab, float* __restrict__ out_g)
{
    __shared__ __align__(16) char smem[A2_SMEM];

    const int tid  = threadIdx.x;
    const int lane = tid & 63;
    const int wv   = tid >> 6;
    const int win  = blockIdx.x;
    const char* qn = qn_g + (size_t)win * 196608;
    const char* kn = kn_g + (size_t)win * 98304;
    const char* vn = vn_g + (size_t)win * 98304;
    char* preb = (char*)out_g + (size_t)win * 196608 + 98304;

    const int l15 = lane & 15, l4 = lane >> 4;
    const int qt = wv >> 1, half = wv & 1;
    const int qA  = qt*16 + l15;
    const int kA0 = half*32 + l15;
    const int kA1 = kA0 + 16;

    // mask regs + bias indices (head-invariant)
    const float* mask_w = mask_g + (size_t)(win & 63) * NPAT * NPAT;
    f32x4 mk0 = *(const f32x4*)(mask_w + qA*64 + half*32 + l4*4);
    f32x4 mk1 = *(const f32x4*)(mask_w + qA*64 + half*32 + 16 + l4*4);
    int bidx[8];
    {
        int qh = qA >> 3, qw = qA & 7;
        #pragma unroll
        for (int kt = 0; kt < 2; ++kt)
            #pragma unroll
            for (int r = 0; r < 4; ++r) {
                int kc = (half*2 + kt)*16 + l4*4 + r;
                bidx[kt*4+r] = ((qh - (kc>>3) + 7)*15 + (qw - (kc&7) + 7)) * NHEAD;
            }
    }

    for (int h = 0; h < NHEAD; ++h) {
        // ---- stepA: QK^T (swapped) + per-lane softmax ----
        float bload[8];
        #pragma unroll
        for (int i = 0; i < 8; ++i) bload[i] = btab[bidx[i] + h];

        f32x4 acc0 = {0.f,0.f,0.f,0.f};
        f32x4 acc1 = {0.f,0.f,0.f,0.f};
        {
            const char* qrow  = qn + (size_t)(h*64 + qA )*256 + l4*16;
            const char* krow0 = kn + (size_t)(h*64 + kA0)*256 + l4*16;
            const char* krow1 = kn + (size_t)(h*64 + kA1)*256 + l4*16;
            __builtin_amdgcn_s_setprio(1);
            #pragma unroll
            for (int ks = 0; ks < 4; ++ks) {
                s16x8 bf = *(const s16x8*)(qrow  + ks*64);
                s16x8 a0 = *(const s16x8*)(krow0 + ks*64);
                s16x8 a1 = *(const s16x8*)(krow1 + ks*64);
                acc0 = mfma16(a0, bf, acc0);
                acc1 = mfma16(a1, bf, acc1);
            }
            __builtin_amdgcn_s_setprio(0);
        }
        {
            float P[8];
            #pragma unroll
            for (int r = 0; r < 4; ++r) {
                P[r]   = acc0[r] + mk0[r] + bload[r];
                P[4+r] = acc1[r] + mk1[r] + bload[4+r];
            }
            float m = fmaxf(fmaxf(fmaxf(P[0],P[1]), fmaxf(P[2],P[3])),
                            fmaxf(fmaxf(P[4],P[5]), fmaxf(P[6],P[7])));
            m = fmaxf(m, __shfl_xor(m, 16));
            m = fmaxf(m, __shfl_xor(m, 32));
            float s = 0.f;
            #pragma unroll
            for (int i = 0; i < 8; ++i) { P[i] = __expf(P[i] - m); s += P[i]; }
            s += __shfl_xor(s, 16);
            s += __shfl_xor(s, 32);
            if (l4 == 0) {
                float2 v; v.x = m; v.y = s;
                *(float2*)(smem + A2_HB + qA*16 + half*8) = v;
            }
            #pragma unroll
            for (int kt = 0; kt < 2; ++kt) {
                uint2 pk;
                pk.x = (unsigned)f2bf(P[kt*4+0]) | ((unsigned)f2bf(P[kt*4+1]) << 16);
                pk.y = (unsigned)f2bf(P[kt*4+2]) | ((unsigned)f2bf(P[kt*4+3]) << 16);
                *(uint2*)(smem + A2_PB + qA*128 +
                    (((half*2 + kt)*32 + l4*8) ^ ((qA & 7) << 4))) = pk;
            }
        }
        __syncthreads();   // barrier 1: PB + HB ready

        // ---- stepB: PV (swapped) + rescale-combine -> OB ----
        {
            f32x4 hb = *(const f32x4*)(smem + A2_HB + qA*16); // m0,s0,m1,s1
            float M  = fmaxf(hb[0], hb[2]);
            float w0 = __expf(hb[0] - M), w1 = __expf(hb[2] - M);
            float Sv = 1.f / (hb[1]*w0 + hb[3]*w1);
            float f0 = w0*Sv, f1 = w1*Sv;
            s16x8 pb0 = *(const s16x8*)(smem + A2_PB + qA*128 +
                          ((l4*16) ^ ((qA & 7) << 4)));
            s16x8 pb1 = *(const s16x8*)(smem + A2_PB + qA*128 +
                          ((64 + l4*16) ^ ((qA & 7) << 4)));
            const char* vbase = vn + (size_t)h*16384 + l4*16;
            __builtin_amdgcn_s_setprio(1);
            #pragma unroll
            for (int i = 0; i < 4; ++i) {
                int sct = half*4 + i;
                int scr = sct*16 + l15;
                s16x8 a0 = *(const s16x8*)(vbase + scr*128);
                s16x8 a1 = *(const s16x8*)(vbase + scr*128 + 64);
                f32x4 z = {0.f,0.f,0.f,0.f};
                f32x4 c0 = mfma16(a0, pb0, z);
                f32x4 c1 = mfma16(a1, pb1, z);
                float o0 = f0*c0[0] + f1*c1[0];
                float o1 = f0*c0[1] + f1*c1[1];
                float o2 = f0*c0[2] + f1*c1[2];
                float o3 = f0*c0[3] + f1*c1[3];
                uint2 pk;
                pk.x = (unsigned)f2bf(o0) | ((unsigned)f2bf(o1) << 16);
                pk.y = (unsigned)f2bf(o2) | ((unsigned)f2bf(o3) << 16);
                *(uint2*)(smem + A2_OB + qA*A2_OBS + sct*32 + l4*8) = pk;
            }
            __builtin_amdgcn_s_setprio(0);
        }
        __syncthreads();   // barrier 2: OB ready; PB/HB reads done

        // ---- stepC: store head slab [qp][sc] as full 256B rows ----
        #pragma unroll
        for (int i = 0; i < 2; ++i) {
            int c = i*512 + tid;
            int qp = c >> 4, ch2 = c & 15;
            s16x8 v = *(const s16x8*)(smem + A2_OB + qp*A2_OBS + ch2*16);
            *(s16x8*)(preb + h*16384 + qp*256 + ch2*16) = v;
        }
        // OB rewritten only after next head's barrier 1; PB/HB after barrier 2.
    }
}

// =====================================================================
// Fallback (ws too small): fused R7-style kernel, spill-free bounds.
// =====================================================================
#define FB_VT0 0
#define FB_VT1 16384
#define FB_PB  32768
#define FB_OB  40960
#define FB_ST  58368
#define FB_HB  59904
#define FB_SMEM 60928
#define FB_OBS 272

__global__ __launch_bounds__(512, 2) void dwa_attn_fb_kernel(
    const float* __restrict__ q_g, const float* __restrict__ k_g,
    const float* __restrict__ v_g, const float* __restrict__ mask_g,
    const float* __restrict__ lnqw, const float* __restrict__ lnqb,
    const float* __restrict__ lnkw, const float* __restrict__ lnkb,
    const float* __restrict__ lnvw, const float* __restrict__ lnvb,
    const float* __restrict__ btab, float* __restrict__ out_g)
{
    __shared__ __align__(16) char smem[FB_SMEM];

    const int tid  = threadIdx.x;
    const int lane = tid & 63;
    const int wv   = tid >> 6;
    const int win  = blockIdx.x;
    const size_t wbase = (size_t)win * LTOK * EMB;
    char* preb = (char*)out_g + (size_t)win * 196608 + 98304;

    float* stats = (float*)(smem + FB_ST);
    const int l15 = lane & 15, l4 = lane >> 4;
    const int qt = wv >> 1, half = wv & 1;
    const int qA  = qt*16 + l15;
    const int kA0 = half*32 + l15;
    const int kA1 = kA0 + 16;

    const float* mask_w = mask_g + (size_t)(win & 63) * NPAT * NPAT;
    f32x4 mk0 = *(const f32x4*)(mask_w + qA*64 + half*32 + l4*4);
    f32x4 mk1 = *(const f32x4*)(mask_w + qA*64 + half*32 + 16 + l4*4);
    int bidx[8];
    {
        int qh = qA >> 3, qw = qA & 7;
        #pragma unroll
        for (int kt = 0; kt < 2; ++kt)
            #pragma unroll
            for (int r = 0; r < 4; ++r) {
                int kc = (half*2 + kt)*16 + l4*4 + r;
                bidx[kt*4+r] = ((qh - (kc>>3) + 7)*15 + (qw - (kc&7) + 7)) * NHEAD;
            }
    }

    {
        float* part = (float*)(smem + FB_OB);
        const int t = tid >> 1, hlf = tid & 1;
        const f32x4* qp = (const f32x4*)(q_g + wbase + t*EMB + hlf*96);
        const f32x4* kp = (const f32x4*)(k_g + wbase + t*EMB + hlf*96);
        const f32x4* vp = (const f32x4*)(v_g + wbase + t*EMB + hlf*96);
        float s1q=0.f,s2q=0.f,s1k=0.f,s2k=0.f,s1v=0.f,s2v=0.f;
        #pragma unroll 4
        for (int i = 0; i < 24; ++i) {
            f32x4 a = qp[i];
            s1q += a[0]+a[1]+a[2]+a[3];
            s2q += a[0]*a[0]+a[1]*a[1]+a[2]*a[2]+a[3]*a[3];
            f32x4 b = kp[i];
            s1k += b[0]+b[1]+b[2]+b[3];
            s2k += b[0]*b[0]+b[1]*b[1]+b[2]*b[2]+b[3]*b[3];
            f32x4 c = vp[i];
            s1v += c[0]+c[1]+c[2]+c[3];
            s2v += c[0]*c[0]+c[1]*c[1]+c[2]*c[2]+c[3]*c[3];
        }
        float* pp = part + (t*2 + hlf)*6;
        pp[0]=s1q; pp[1]=s2q; pp[2]=s1k; pp[3]=s2k; pp[4]=s1v; pp[5]=s2v;
        __syncthreads();
        if (tid < NPAT) {
            float S[6] = {0.f,0.f,0.f,0.f,0.f,0.f};
            #pragma unroll
            for (int s = 0; s < 4; ++s) {
                int tt = tok_of(tid, s);
                const float* pr_ = part + tt*12;
                #pragma unroll
                for (int x = 0; x < 6; ++x) S[x] += pr_[x] + pr_[6 + x];
            }
            #pragma unroll
            for (int x = 0; x < 3; ++x) {
                float mu  = S[2*x] * (1.f/768.f);
                float var = S[2*x+1] * (1.f/768.f) - mu*mu;
                stats[x*128 + tid]      = mu;
                stats[x*128 + 64 + tid] = rsqrtf(var + LN_EPS);
            }
        }
        __syncthreads();
    }

    {
        float vld[2][8];
        vload(vld, v_g, wbase, tid, 0);
        vstage(smem + FB_VT0, vld, tid, 0, stats, lnvw, lnvb);
    }

    const float muqv = stats[qA],        rsqv = stats[64 + qA];
    const float muk0 = stats[128 + kA0], rsk0 = stats[192 + kA0];
    const float muk1 = stats[128 + kA1], rsk1 = stats[192 + kA1];

    for (int h = 0; h < NHEAD; ++h) {
        float bload[8];
        #pragma unroll
        for (int i = 0; i < 8; ++i) bload[i] = btab[bidx[i] + h];

        f32x4 acc0 = {0.f,0.f,0.f,0.f};
        f32x4 acc1 = {0.f,0.f,0.f,0.f};
        {
            const int ch = h*HDIM + l4*8;
            #pragma unroll
            for (int ks = 0; ks < 4; ++ks) {
                const float* qp_ = q_g + wbase + tok_of(qA,  ks)*EMB + ch;
                const float* kp0 = k_g + wbase + tok_of(kA0, ks)*EMB + ch;
                const float* kp1 = k_g + wbase + tok_of(kA1, ks)*EMB + ch;
                float qv[8], kv0[8], kv1[8];
                *(f32x4*)&qv[0]  = *(const f32x4*)qp_;
                *(f32x4*)&qv[4]  = *(const f32x4*)(qp_ + 4);
                *(f32x4*)&kv0[0] = *(const f32x4*)kp0;
                *(f32x4*)&kv0[4] = *(const f32x4*)(kp0 + 4);
                *(f32x4*)&kv1[0] = *(const f32x4*)kp1;
                *(f32x4*)&kv1[4] = *(const f32x4*)(kp1 + 4);
                const float* lwq = lnqw + ks*EMB + ch;
                const float* lbq = lnqb + ks*EMB + ch;
                const float* lwk = lnkw + ks*EMB + ch;
                const float* lbk = lnkb + ks*EMB + ch;
                s16x8 bf = ln_pack8r(qv,  muqv, rsqv, lwq, lbq, SCALE);
                s16x8 a0 = ln_pack8r(kv0, muk0, rsk0, lwk, lbk, 1.0f);
                s16x8 a1 = ln_pack8r(kv1, muk1, rsk1, lwk, lbk, 1.0f);
                acc0 = mfma16(a0, bf, acc0);
                acc1 = mfma16(a1, bf, acc1);
            }
        }
        {
            float P[8];
            #pragma unroll
            for (int r = 0; r < 4; ++r) {
                P[r]   = acc0[r] + mk0[r] + bload[r];
                P[4+r] = acc1[r] + mk1[r] + bload[4+r];
            }
            float m = fmaxf(fmaxf(fmaxf(P[0],P[1]), fmaxf(P[2],P[3])),
                            fmaxf(fmaxf(P[4],P[5]), fmaxf(P[6],P[7])));
            m = fmaxf(m, __shfl_xor(m, 16));
            m = fmaxf(m, __shfl_xor(m, 32));
            float s = 0.f;
            #pragma unroll
            for (int i = 0; i < 8; ++i) { P[i] = __expf(P[i] - m); s += P[i]; }
            s += __shfl_xor(s, 16);
            s += __shfl_xor(s, 32);
            if (l4 == 0) {
                float2 v; v.x = m; v.y = s;
                *(float2*)(smem + FB_HB + qA*16 + half*8) = v;
            }
            #pragma unroll
            for (int kt = 0; kt < 2; ++kt) {
                uint2 pk;
                pk.x = (unsigned)f2bf(P[kt*4+0]) | ((unsigned)f2bf(P[kt*4+1]) << 16);
                pk.y = (unsigned)f2bf(P[kt*4+2]) | ((unsigned)f2bf(P[kt*4+3]) << 16);
                *(uint2*)(smem + FB_PB + qA*128 +
                    (((half*2 + kt)*32 + l4*8) ^ ((qA & 7) << 4))) = pk;
            }
        }
        __syncthreads();

        float vld[2][8];
        if (h < NHEAD-1) vload(vld, v_g, wbase, tid, h+1);
        {
            f32x4 hb = *(const f32x4*)(smem + FB_HB + qA*16);
            float M  = fmaxf(hb[0], hb[2]);
            float w0 = __expf(hb[0] - M), w1 = __expf(hb[2] - M);
            float Sv = 1.f / (hb[1]*w0 + hb[3]*w1);
            float f0 = w0*Sv, f1 = w1*Sv;
            s16x8 pb0 = *(const s16x8*)(smem + FB_PB + qA*128 +
                          ((l4*16) ^ ((qA & 7) << 4)));
            s16x8 pb1 = *(const s16x8*)(smem + FB_PB + qA*128 +
                          ((64 + l4*16) ^ ((qA & 7) << 4)));
            const char* vt = smem + ((h & 1) ? FB_VT1 : FB_VT0);
            #pragma unroll
            for (int i = 0; i < 4; ++i) {
                int sct = half*4 + i;
                int scr = sct*16 + l15;
                s16x8 a0 = *(const s16x8*)(vt + scr*128 +
                              ((l4*16) ^ ((scr & 7) << 4)));
                s16x8 a1 = *(const s16x8*)(vt + scr*128 +
                              ((64 + l4*16) ^ ((scr & 7) << 4)));
                f32x4 z = {0.f,0.f,0.f,0.f};
                f32x4 c0 = mfma16(a0, pb0, z);
                f32x4 c1 = mfma16(a1, pb1, z);
                float o0 = f0*c0[0] + f1*c1[0];
                float o1 = f0*c0[1] + f1*c1[1];
                float o2 = f0*c0[2] + f1*c1[2];
                float o3 = f0*c0[3] + f1*c1[3];
                uint2 pk;
                pk.x = (unsigned)f2bf(o0) | ((unsigned)f2bf(o1) << 16);
                pk.y = (unsigned)f2bf(o2) | ((unsigned)f2bf(o3) << 16);
                *(uint2*)(smem + FB_OB + qA*FB_OBS + sct*32 + l4*8) = pk;
            }
        }
        if (h < NHEAD-1)
            vstage(smem + ((h & 1) ? FB_VT0 : FB_VT1), vld, tid, h+1,
                   stats, lnvw, lnvb);
        __syncthreads();

        #pragma unroll
        for (int i = 0; i < 2; ++i) {
            int c = i*512 + tid;
            int qp = c >> 4, ch2 = c & 15;
            s16x8 v = *(const s16x8*)(smem + FB_OB + qp*FB_OBS + ch2*16);
            *(s16x8*)(preb + h*16384 + qp*256 + ch2*16) = v;
        }
    }
}

// ---- projection: 1 block per window, W staged bf16 in LDS once ----
__global__ __launch_bounds__(256, 2) void dwa_proj_kernel(
    const float* __restrict__ pw, float* __restrict__ out_g)
{
    __shared__ __align__(16) char smem[73728];   // [192 orow][192 ch] bf16, swz

    const int tid  = threadIdx.x;
    const int lane = tid & 63;
    const int wv   = tid >> 6;
    const int w    = blockIdx.x;
    const char* preb = (const char*)out_g + (size_t)w * 196608 + 98304;
    const int cb = lane >> 4;

    s16x8 af[4][6];
    #pragma unroll
    for (int si = 0; si < 4; ++si) {
        int t = (wv*4 + si)*16 + (lane & 15);
        int qp = ((t >> 5) << 3) | ((t >> 1) & 7);
        int s  = (((t >> 4) & 1) << 1) | (t & 1);
        #pragma unroll
        for (int ks = 0; ks < 6; ++ks)
            af[si][ks] = *(const s16x8*)(preb + ks*16384 + qp*256 + s*64 + cb*16);
    }

    #pragma unroll 2
    for (int i = 0; i < 18; ++i) {
        int c = i*256 + tid;
        int orow = c / 24, cb8 = c % 24;
        const float* wp = pw + (size_t)orow*EMB + cb8*8;
        f32x4 a = *(const f32x4*)wp;
        f32x4 b = *(const f32x4*)(wp + 4);
        s16x8 w8;
        w8[0] = (short)f2bf(a[0]); w8[1] = (short)f2bf(a[1]);
        w8[2] = (short)f2bf(a[2]); w8[3] = (short)f2bf(a[3]);
        w8[4] = (short)f2bf(b[0]); w8[5] = (short)f2bf(b[1]);
        w8[6] = (short)f2bf(b[2]); w8[7] = (short)f2bf(b[3]);
        *(s16x8*)(smem + orow*384 + ((cb8*16) ^ ((orow & 7) << 4))) = w8;
    }
    __syncthreads();

    #pragma unroll
    for (int si = 0; si < 4; ++si) {
        int strip = wv*4 + si;
        #pragma unroll
        for (int nt = 0; nt < 12; ++nt) {
            int orow = nt*16 + (lane & 15);
            f32x4 acc = {0.f,0.f,0.f,0.f};
            #pragma unroll
            for (int ks = 0; ks < 6; ++ks) {
                s16x8 bf = *(const s16x8*)(smem + orow*384 +
                              ((ks*64 + cb*16) ^ ((orow & 7) << 4)));
                acc = mfma16(af[si][ks], bf, acc);
            }
            #pragma unroll
            for (int r = 0; r < 4; ++r) {
                int trow = strip*16 + (lane >> 4)*4 + r;
                out_g[(size_t)w*49152 + trow*EMB + nt*16 + (lane & 15)] = acc[r];
            }
        }
    }
}

extern "C" void kernel_launch(void* const* d_in, const int* in_sizes, int n_in,
                              void* d_out, int out_size, void* d_ws, size_t ws_size,
                              hipStream_t stream) {
    (void)in_sizes; (void)n_in; (void)out_size;
    const float* q_g  = (const float*)d_in[0];
    const float* k_g  = (const float*)d_in[1];
    const float* v_g  = (const float*)d_in[2];
    const float* mask = (const float*)d_in[3];
    const float* lnqw = (const float*)d_in[4];
    const float* lnqb = (const float*)d_in[5];
    const float* lnkw = (const float*)d_in[6];
    const float* lnkb = (const float*)d_in[7];
    const float* lnvw = (const float*)d_in[8];
    const float* lnvb = (const float*)d_in[9];
    const float* btab = (const float*)d_in[10];
    const float* pw   = (const float*)d_in[11];

    if (ws_size >= 2*KN_BYTES) {
        char* kn = (char*)d_ws;
        char* vn = (char*)d_ws + KN_BYTES;
        dwa_prep_kernel<<<dim3(NWIN), dim3(512), 0, stream>>>(
            q_g, k_g, v_g, lnqw, lnqb, lnkw, lnkb, lnvw, lnvb,
            (char*)d_out, kn, vn);
        dwa_attn2_kernel<<<dim3(NWIN), dim3(512), 0, stream>>>(
            (const char*)d_out, kn, vn, mask, btab, (float*)d_out);
    } else {
        dwa_attn_fb_kernel<<<dim3(NWIN), dim3(512), 0, stream>>>(
            q_g, k_g, v_g, mask, lnqw, lnqb, lnkw, lnkb, lnvw, lnvb,
            btab, (float*)d_out);
    }
    dwa_proj_kernel<<<dim3(NWIN), dim3(256), 0, stream>>>(pw, (float*)d_out);
}